// Round 2
// baseline (316.303 us; speedup 1.0000x reference)
//
#include <hip/hip_runtime.h>

#define BT_ (8 * 2048)
#define T_  2048
#define H_  64

// ---------------------------------------------------------------------------
// Kernel 1: fused QKV projection (f32 exact)
// x:[16384,1024] @ W{q,k,v}:[1024,64] -> qkv ws: Q|K|V each [16384,64]
// grid 256, block 256. Block tile: 64 rows x 192 cols. Thread tile: 4r x 12c.
// K staged in chunks of 32 (xT transposed for b128 row reads).
// ---------------------------------------------------------------------------
__global__ __launch_bounds__(256) void qkv_proj(
    const float* __restrict__ x,
    const float* __restrict__ Wq,
    const float* __restrict__ Wk,
    const float* __restrict__ Wv,
    float* __restrict__ qkv) {
  __shared__ float xT[32][68];    // [k][row], stride 68 -> conflict-free b128 reads
  __shared__ float wl[32][196];   // [k][192 cols], stride 196

  const int tid = threadIdx.x;
  const int tx = tid & 15;   // col group: cols tx*12 .. +11
  const int ty = tid >> 4;   // row group: rows ty*4 .. +3
  const int row0 = blockIdx.x * 64;

  float acc[4][12];
#pragma unroll
  for (int r = 0; r < 4; ++r)
#pragma unroll
    for (int c = 0; c < 12; ++c) acc[r][c] = 0.f;

  for (int kc = 0; kc < 1024; kc += 32) {
    // stage x chunk, transposed: 64 rows x 32 k
#pragma unroll
    for (int i = 0; i < 2; ++i) {
      int idx = tid + i * 256;
      int r = idx >> 3;
      int k4 = (idx & 7) * 4;
      const float4 v = *reinterpret_cast<const float4*>(
          &x[(size_t)(row0 + r) * 1024 + kc + k4]);
      xT[k4 + 0][r] = v.x;
      xT[k4 + 1][r] = v.y;
      xT[k4 + 2][r] = v.z;
      xT[k4 + 3][r] = v.w;
    }
    // stage W chunk: 32 k x (64 q | 64 k | 64 v)
    {
      const float* wp[3] = {Wq, Wk, Wv};
#pragma unroll
      for (int m = 0; m < 3; ++m) {
#pragma unroll
        for (int i = 0; i < 2; ++i) {
          int idx = tid + i * 256;
          int r = idx >> 4;
          int h4 = (idx & 15) * 4;
          const float4 v = *reinterpret_cast<const float4*>(
              &wp[m][(size_t)(kc + r) * 64 + h4]);
          *reinterpret_cast<float4*>(&wl[r][m * 64 + h4]) = v;
        }
      }
    }
    __syncthreads();

#pragma unroll
    for (int kk = 0; kk < 32; ++kk) {
      const float4 xv = *reinterpret_cast<const float4*>(&xT[kk][ty * 4]);
      const float4 w0 = *reinterpret_cast<const float4*>(&wl[kk][tx * 12 + 0]);
      const float4 w1 = *reinterpret_cast<const float4*>(&wl[kk][tx * 12 + 4]);
      const float4 w2 = *reinterpret_cast<const float4*>(&wl[kk][tx * 12 + 8]);
      const float xr[4] = {xv.x, xv.y, xv.z, xv.w};
      const float wr[12] = {w0.x, w0.y, w0.z, w0.w, w1.x, w1.y, w1.z, w1.w,
                            w2.x, w2.y, w2.z, w2.w};
#pragma unroll
      for (int r = 0; r < 4; ++r)
#pragma unroll
        for (int c = 0; c < 12; ++c)
          acc[r][c] = fmaf(xr[r], wr[c], acc[r][c]);
    }
    __syncthreads();
  }

  // epilogue: scatter 4x12 into Q/K/V planes of ws
#pragma unroll
  for (int r = 0; r < 4; ++r) {
#pragma unroll
    for (int g = 0; g < 3; ++g) {
      const int col = tx * 12 + g * 4;
      const int m = col >> 6;     // 0=Q 1=K 2=V (float4 never crosses a plane)
      const int h = col & 63;
      float4 v = make_float4(acc[r][g * 4 + 0], acc[r][g * 4 + 1],
                             acc[r][g * 4 + 2], acc[r][g * 4 + 3]);
      *reinterpret_cast<float4*>(
          &qkv[(size_t)m * BT_ * H_ + (size_t)(row0 + ty * 4 + r) * H_ + h]) = v;
    }
  }
}

// ---------------------------------------------------------------------------
// Kernel 2: causal flash attention (f32 exact, online softmax)
// grid 512 (8 batches x 64 q-tiles of 32 rows), block 256.
// Per k-tile (64 rows): S = qT.kT in-register (thread: 2 q-rows x 4 k-cols),
// shfl row-reduce softmax across the 16 tx lanes, P via LDS, PV accumulate.
// blockIdx -> qt DESCENDING so long blocks dispatch first (LPT balance).
// ---------------------------------------------------------------------------
__global__ __launch_bounds__(256) void attn_fwd(
    const float* __restrict__ qkv, float* __restrict__ out) {
  __shared__ float qT[64][36];  // [h][qrow]  (pre-scaled by 1/32)
  __shared__ float kT[64][68];  // [h][krow]
  __shared__ float vl[64][68];  // [krow][h]
  __shared__ float pT[64][36];  // [krow][qrow]

  const int tid = threadIdx.x;
  const int tx = tid & 15;    // k-cols tx*4 .. +3  /  h-cols tx*4 .. +3
  const int ty = tid >> 4;    // q-rows ty*2 .. +1
  const int b  = blockIdx.x & 7;
  const int qt = 63 - (blockIdx.x >> 3);
  const int r0 = qt * 32;

  const float* Q = qkv;
  const float* K = qkv + (size_t)BT_ * H_;
  const float* V = qkv + (size_t)2 * BT_ * H_;

  // stage q tile transposed, folding the 1/sqrt(C)=1/32 scale
#pragma unroll
  for (int i = 0; i < 2; ++i) {
    int idx = tid + i * 256;
    int r = idx >> 4;
    int h4 = (idx & 15) * 4;
    float4 v = *reinterpret_cast<const float4*>(
        &Q[((size_t)b * T_ + r0 + r) * H_ + h4]);
    qT[h4 + 0][r] = v.x * 0.03125f;
    qT[h4 + 1][r] = v.y * 0.03125f;
    qT[h4 + 2][r] = v.z * 0.03125f;
    qT[h4 + 3][r] = v.w * 0.03125f;
  }

  float m0 = -1e30f, m1 = -1e30f, l0 = 0.f, l1 = 0.f;
  float o0[4] = {0, 0, 0, 0}, o1[4] = {0, 0, 0, 0};

  const int nkt = qt / 2 + 1;
  for (int kt = 0; kt < nkt; ++kt) {
    // stage K (transposed) and V (row-major) tiles
#pragma unroll
    for (int i = 0; i < 4; ++i) {
      int idx = tid + i * 256;
      int j = idx >> 4;
      int h4 = (idx & 15) * 4;
      size_t g = ((size_t)b * T_ + kt * 64 + j) * H_ + h4;
      float4 kv = *reinterpret_cast<const float4*>(&K[g]);
      kT[h4 + 0][j] = kv.x;
      kT[h4 + 1][j] = kv.y;
      kT[h4 + 2][j] = kv.z;
      kT[h4 + 3][j] = kv.w;
      *reinterpret_cast<float4*>(&vl[j][h4]) =
          *reinterpret_cast<const float4*>(&V[g]);
    }
    __syncthreads();  // also covers qT on first iteration

    // S = q . k  (2 rows x 4 cols per thread)
    float s0[4] = {0, 0, 0, 0}, s1[4] = {0, 0, 0, 0};
#pragma unroll
    for (int h = 0; h < 64; ++h) {
      float2 qv = *reinterpret_cast<const float2*>(&qT[h][ty * 2]);
      float4 kv = *reinterpret_cast<const float4*>(&kT[h][tx * 4]);
      const float kr[4] = {kv.x, kv.y, kv.z, kv.w};
#pragma unroll
      for (int c = 0; c < 4; ++c) {
        s0[c] = fmaf(qv.x, kr[c], s0[c]);
        s1[c] = fmaf(qv.y, kr[c], s1[c]);
      }
    }

    // causal mask — only the diagonal k-tile can clip
    if (kt == nkt - 1) {
      const int rg = r0 + ty * 2;
#pragma unroll
      for (int c = 0; c < 4; ++c) {
        const int jg = kt * 64 + tx * 4 + c;
        if (jg > rg)     s0[c] = -1e30f;
        if (jg > rg + 1) s1[c] = -1e30f;
      }
    }

    // online softmax: row max / sum across the 16 tx lanes
    float mt0 = fmaxf(fmaxf(s0[0], s0[1]), fmaxf(s0[2], s0[3]));
    float mt1 = fmaxf(fmaxf(s1[0], s1[1]), fmaxf(s1[2], s1[3]));
#pragma unroll
    for (int d = 1; d < 16; d <<= 1) {
      mt0 = fmaxf(mt0, __shfl_xor(mt0, d));
      mt1 = fmaxf(mt1, __shfl_xor(mt1, d));
    }
    const float mn0 = fmaxf(m0, mt0), mn1 = fmaxf(m1, mt1);
    const float a0 = __expf(m0 - mn0), a1 = __expf(m1 - mn1);
    float p0[4], p1[4], sum0 = 0.f, sum1 = 0.f;
#pragma unroll
    for (int c = 0; c < 4; ++c) {
      p0[c] = __expf(s0[c] - mn0);
      p1[c] = __expf(s1[c] - mn1);
      sum0 += p0[c];
      sum1 += p1[c];
    }
#pragma unroll
    for (int d = 1; d < 16; d <<= 1) {
      sum0 += __shfl_xor(sum0, d);
      sum1 += __shfl_xor(sum1, d);
    }
    l0 = l0 * a0 + sum0;
    l1 = l1 * a1 + sum1;
    m0 = mn0;
    m1 = mn1;
#pragma unroll
    for (int c = 0; c < 4; ++c) {
      o0[c] *= a0;
      o1[c] *= a1;
    }

    // publish P transposed for the PV pass
#pragma unroll
    for (int c = 0; c < 4; ++c) {
      pT[tx * 4 + c][ty * 2 + 0] = p0[c];
      pT[tx * 4 + c][ty * 2 + 1] = p1[c];
    }
    __syncthreads();

    // O += P . V   (thread: 2 rows x 4 h-cols)
#pragma unroll
    for (int j = 0; j < 64; ++j) {
      float2 pv = *reinterpret_cast<const float2*>(&pT[j][ty * 2]);
      float4 vv = *reinterpret_cast<const float4*>(&vl[j][tx * 4]);
      const float vr[4] = {vv.x, vv.y, vv.z, vv.w};
#pragma unroll
      for (int c = 0; c < 4; ++c) {
        o0[c] = fmaf(pv.x, vr[c], o0[c]);
        o1[c] = fmaf(pv.y, vr[c], o1[c]);
      }
    }
    __syncthreads();  // vl/pT consumed before next stage
  }

  const float inv0 = 1.0f / l0, inv1 = 1.0f / l1;
  const size_t orow = ((size_t)b * T_ + r0 + ty * 2) * H_ + tx * 4;
  *reinterpret_cast<float4*>(&out[orow]) =
      make_float4(o0[0] * inv0, o0[1] * inv0, o0[2] * inv0, o0[3] * inv0);
  *reinterpret_cast<float4*>(&out[orow + H_]) =
      make_float4(o1[0] * inv1, o1[1] * inv1, o1[2] * inv1, o1[3] * inv1);
}

extern "C" void kernel_launch(void* const* d_in, const int* in_sizes, int n_in,
                              void* d_out, int out_size, void* d_ws,
                              size_t ws_size, hipStream_t stream) {
  const float* x  = (const float*)d_in[0];
  const float* Wq = (const float*)d_in[1];
  const float* Wk = (const float*)d_in[2];
  const float* Wv = (const float*)d_in[3];
  float* ws  = (float*)d_ws;   // Q | K | V planes, 3 * 16384*64 f32 = 12 MB
  float* out = (float*)d_out;

  qkv_proj<<<256, 256, 0, stream>>>(x, Wq, Wk, Wv, ws);
  attn_fwd<<<512, 256, 0, stream>>>(ws, out);
}